// Round 1
// baseline (337.160 us; speedup 1.0000x reference)
//
#include <hip/hip_runtime.h>

#define B_  4
#define C_  512
#define CQ_ 64
#define N_  4096

typedef _Float16 half8 __attribute__((ext_vector_type(8)));
typedef float    f32x4 __attribute__((ext_vector_type(4)));

// ---------------------------------------------------------------------------
// Kernel 1: fused QKV projection.  Out(ch, n) = W(ch, c) * x(c, n) per batch.
// Virtual ch rows: [0,64)=Q, [64,128)=K, [128,640)=V.
// Q, K stored n-major: Qh[b][n][cq]  (so flash reads contiguous cq)
// V stored d-major:   Vh[b][d][m]   (so flash PV A-frag reads contiguous m)
// ---------------------------------------------------------------------------
__global__ __launch_bounds__(256) void proj_kernel(
    const float* __restrict__ x,  const float* __restrict__ Wq,
    const float* __restrict__ Wk, const float* __restrict__ Wv,
    _Float16* __restrict__ Qh, _Float16* __restrict__ Kh, _Float16* __restrict__ Vh)
{
  __shared__ _Float16 As[64][40];   // W tile  (64 ch x 32 c), pad to 40
  __shared__ _Float16 Bs[64][40];   // x tile transposed (64 n x 32 c)

  const int tid = threadIdx.x;
  const int wid = tid >> 6, lane = tid & 63, ln = lane & 15, lh = lane >> 4;
  const int nBase  = blockIdx.x * 64;
  const int chTile = blockIdx.y;
  const int b      = blockIdx.z;

  const float* Wsrc;
  if (chTile == 0)      Wsrc = Wq;
  else if (chTile == 1) Wsrc = Wk;
  else                  Wsrc = Wv + (size_t)(chTile - 2) * 64 * C_;

  f32x4 acc[4] = {};

  const int ar = tid >> 2, ac = (tid & 3) * 8;   // A staging: 64 rows x 4 chunks
  const int bc = tid >> 3, bn = (tid & 7) * 8;   // B staging: 32 c-rows x 8 n-chunks

  for (int kt = 0; kt < C_; kt += 32) {
    __syncthreads();
    {   // stage A (fp32 -> fp16)
      const float* src = Wsrc + (size_t)ar * C_ + kt + ac;
      #pragma unroll
      for (int u = 0; u < 8; ++u) As[ar][ac + u] = (_Float16)src[u];
    }
    {   // stage B transposed (x is (c, n) row-major in n)
      const float* src = x + ((size_t)b * C_ + kt + bc) * N_ + nBase + bn;
      #pragma unroll
      for (int u = 0; u < 8; ++u) Bs[bn + u][bc] = (_Float16)src[u];
    }
    __syncthreads();
    half8 a = *(const half8*)&As[wid * 16 + ln][lh * 8];
    #pragma unroll
    for (int ct = 0; ct < 4; ++ct) {
      half8 bf = *(const half8*)&Bs[ct * 16 + ln][lh * 8];
      acc[ct] = __builtin_amdgcn_mfma_f32_16x16x32_f16(a, bf, acc[ct], 0, 0, 0);
    }
  }

  #pragma unroll
  for (int ct = 0; ct < 4; ++ct) {
    const int n = nBase + ct * 16 + ln;
    #pragma unroll
    for (int j = 0; j < 4; ++j) {
      const int chL = wid * 16 + lh * 4 + j;      // D row = (lane>>4)*4 + reg
      const _Float16 v = (_Float16)acc[ct][j];
      if (chTile == 0)      Qh[((size_t)b * N_ + n) * CQ_ + chL] = v;
      else if (chTile == 1) Kh[((size_t)b * N_ + n) * CQ_ + chL] = v;
      else                  Vh[((size_t)b * C_ + (chTile - 2) * 64 + chL) * N_ + n] = v;
    }
  }
}

// ---------------------------------------------------------------------------
// Kernel 2: flash attention.  Block = (b, 32 query rows n) x all 512 d.
// acc[d][n] = sum_m V[d][m] * exp(E[n][m] - max) ;  out = gamma*acc/l + x
// 4 waves: wave w owns d range [w*128, w*128+128), all share P tile via LDS.
// ---------------------------------------------------------------------------
__global__ __launch_bounds__(256) void flash_kernel(
    const float* __restrict__ x, const _Float16* __restrict__ Qh,
    const _Float16* __restrict__ Kh, const _Float16* __restrict__ Vh,
    const float* __restrict__ gamma, float* __restrict__ out)
{
  __shared__ float    Es[32][68];   // raw energies (fp32), pad 4
  __shared__ _Float16 Ps[32][72];   // exp weights (fp16),  pad 8
  __shared__ float    m_s[32], l_s[32], sc_s[32];

  const int tid = threadIdx.x;
  const int wid = tid >> 6, lane = tid & 63, ln = lane & 15, lh = lane >> 4;

  // bijective XCD swizzle: 512 blocks, 64 consecutive (same-b) blocks per XCD
  const int wg = (blockIdx.x & 7) * 64 + (blockIdx.x >> 3);
  const int b  = wg >> 7;            // 128 n-tiles per batch
  const int n0 = (wg & 127) * 32;
  const int d0w = wid * 128;

  if (tid < 32) { m_s[tid] = -3.0e38f; l_s[tid] = 0.0f; }

  // preload Q fragments (constant over the whole m loop)
  half8 qf[2][2];
  #pragma unroll
  for (int rt = 0; rt < 2; ++rt)
    #pragma unroll
    for (int kk = 0; kk < 2; ++kk)
      qf[rt][kk] = *(const half8*)&Qh[((size_t)b * N_ + n0 + rt * 16 + ln) * CQ_ + kk * 32 + lh * 8];

  f32x4 acc[8][2] = {};
  __syncthreads();

  for (int m0 = 0; m0 < N_; m0 += 64) {
    // ---- Phase 1: energy tile E(32 x 64); wave w computes cols [w*16, w*16+16)
    {
      const int mm = m0 + wid * 16 + ln;
      const size_t kb = ((size_t)b * N_ + mm) * CQ_ + lh * 8;
      half8 kf0 = *(const half8*)&Kh[kb];
      half8 kf1 = *(const half8*)&Kh[kb + 32];
      #pragma unroll
      for (int rt = 0; rt < 2; ++rt) {
        f32x4 e = {};
        e = __builtin_amdgcn_mfma_f32_16x16x32_f16(qf[rt][0], kf0, e, 0, 0, 0);
        e = __builtin_amdgcn_mfma_f32_16x16x32_f16(qf[rt][1], kf1, e, 0, 0, 0);
        #pragma unroll
        for (int j = 0; j < 4; ++j)
          Es[rt * 16 + lh * 4 + j][wid * 16 + ln] = e[j];
      }
    }
    __syncthreads();

    // ---- Phase 2: online softmax; row r = tid>>3 (wave-local), slice s = tid&7
    {
      const int r = tid >> 3, s = tid & 7;
      float ev[8], tmax = -3.0e38f;
      #pragma unroll
      for (int u = 0; u < 8; ++u) { ev[u] = Es[r][s * 8 + u]; tmax = fmaxf(tmax, ev[u]); }
      tmax = fmaxf(tmax, __shfl_xor(tmax, 1));
      tmax = fmaxf(tmax, __shfl_xor(tmax, 2));
      tmax = fmaxf(tmax, __shfl_xor(tmax, 4));
      const float mold = m_s[r];
      const float mnew = fmaxf(mold, tmax);
      const float scale = __expf(mold - mnew);
      float psum = 0.f;
      #pragma unroll
      for (int u = 0; u < 8; ++u) {
        const float p = __expf(ev[u] - mnew);
        Ps[r][s * 8 + u] = (_Float16)p;
        psum += p;
      }
      psum += __shfl_xor(psum, 1);
      psum += __shfl_xor(psum, 2);
      psum += __shfl_xor(psum, 4);
      if (s == 0) { m_s[r] = mnew; l_s[r] = l_s[r] * scale + psum; sc_s[r] = scale; }
    }
    __syncthreads();

    // ---- Phase 3: rescale acc (per column n) + PV MFMA
    {
      const float scl[2] = { sc_s[ln], sc_s[16 + ln] };
      half8 pf[2][2];
      #pragma unroll
      for (int nt2 = 0; nt2 < 2; ++nt2)
        #pragma unroll
        for (int kk = 0; kk < 2; ++kk)
          pf[nt2][kk] = *(const half8*)&Ps[nt2 * 16 + ln][kk * 32 + lh * 8];
      #pragma unroll
      for (int dt = 0; dt < 8; ++dt) {
        const size_t vbase = ((size_t)b * C_ + d0w + dt * 16 + ln) * N_ + m0 + lh * 8;
        half8 vf0 = *(const half8*)&Vh[vbase];
        half8 vf1 = *(const half8*)&Vh[vbase + 32];
        #pragma unroll
        for (int nt2 = 0; nt2 < 2; ++nt2) {
          f32x4 a = acc[dt][nt2];
          const float s0 = scl[nt2];
          a[0] *= s0; a[1] *= s0; a[2] *= s0; a[3] *= s0;
          a = __builtin_amdgcn_mfma_f32_16x16x32_f16(vf0, pf[nt2][0], a, 0, 0, 0);
          a = __builtin_amdgcn_mfma_f32_16x16x32_f16(vf1, pf[nt2][1], a, 0, 0, 0);
          acc[dt][nt2] = a;
        }
      }
    }
    __syncthreads();
  }

  // ---- Epilogue: normalize, gamma*out + x
  const float g = gamma[0];
  const float linv[2] = { 1.0f / l_s[ln], 1.0f / l_s[16 + ln] };
  #pragma unroll
  for (int dt = 0; dt < 8; ++dt) {
    #pragma unroll
    for (int nt2 = 0; nt2 < 2; ++nt2) {
      const int n = n0 + nt2 * 16 + ln;
      #pragma unroll
      for (int j = 0; j < 4; ++j) {
        const int d = d0w + dt * 16 + lh * 4 + j;
        const size_t idx = ((size_t)b * C_ + d) * N_ + n;
        out[idx] = g * acc[dt][nt2][j] * linv[nt2] + x[idx];
      }
    }
  }
}

extern "C" void kernel_launch(void* const* d_in, const int* in_sizes, int n_in,
                              void* d_out, int out_size, void* d_ws, size_t ws_size,
                              hipStream_t stream) {
  const float* x     = (const float*)d_in[0];
  const float* Wq    = (const float*)d_in[1];
  const float* Wk    = (const float*)d_in[2];
  const float* Wv    = (const float*)d_in[3];
  const float* gamma = (const float*)d_in[4];
  float* out = (float*)d_out;

  _Float16* Qh = (_Float16*)d_ws;                       // B*N*CQ fp16 = 2 MB
  _Float16* Kh = Qh + (size_t)B_ * N_ * CQ_;            // 2 MB
  _Float16* Vh = Kh + (size_t)B_ * N_ * CQ_;            // B*C*N fp16 = 16.8 MB

  proj_kernel<<<dim3(64, 10, B_), 256, 0, stream>>>(x, Wq, Wk, Wv, Qh, Kh, Vh);
  flash_kernel<<<dim3(512), 256, 0, stream>>>(x, Qh, Kh, Vh, gamma, out);
}

// Round 2
// 331.062 us; speedup vs baseline: 1.0184x; 1.0184x over previous
//
#include <hip/hip_runtime.h>

#define B_  4
#define C_  512
#define CQ_ 64
#define N_  4096
#define M_  128   // keys per iteration
#define R_  32    // query rows per block

typedef _Float16 half8 __attribute__((ext_vector_type(8)));
typedef _Float16 half4 __attribute__((ext_vector_type(4)));
typedef float    f32x4 __attribute__((ext_vector_type(4)));

// ---------------------------------------------------------------------------
// Kernel 1: fused QKV projection.  Out(ch, n) = W(ch, c) * x(c, n) per batch.
// Q, K stored n-major: Qh[b][n][cq];  V stored d-major: Vh[b][d][m]
// ---------------------------------------------------------------------------
__global__ __launch_bounds__(256) void proj_kernel(
    const float* __restrict__ x,  const float* __restrict__ Wq,
    const float* __restrict__ Wk, const float* __restrict__ Wv,
    _Float16* __restrict__ Qh, _Float16* __restrict__ Kh, _Float16* __restrict__ Vh)
{
  __shared__ _Float16 As[64][40];
  __shared__ _Float16 Bs[64][40];

  const int tid = threadIdx.x;
  const int wid = tid >> 6, lane = tid & 63, ln = lane & 15, lh = lane >> 4;
  const int nBase  = blockIdx.x * 64;
  const int chTile = blockIdx.y;
  const int b      = blockIdx.z;

  const float* Wsrc;
  if (chTile == 0)      Wsrc = Wq;
  else if (chTile == 1) Wsrc = Wk;
  else                  Wsrc = Wv + (size_t)(chTile - 2) * 64 * C_;

  f32x4 acc[4] = {};

  const int ar = tid >> 2, ac = (tid & 3) * 8;
  const int bc = tid >> 3, bn = (tid & 7) * 8;

  for (int kt = 0; kt < C_; kt += 32) {
    __syncthreads();
    {
      const float* src = Wsrc + (size_t)ar * C_ + kt + ac;
      #pragma unroll
      for (int u = 0; u < 8; ++u) As[ar][ac + u] = (_Float16)src[u];
    }
    {
      const float* src = x + ((size_t)b * C_ + kt + bc) * N_ + nBase + bn;
      #pragma unroll
      for (int u = 0; u < 8; ++u) Bs[bn + u][bc] = (_Float16)src[u];
    }
    __syncthreads();
    half8 a = *(const half8*)&As[wid * 16 + ln][lh * 8];
    #pragma unroll
    for (int ct = 0; ct < 4; ++ct) {
      half8 bf = *(const half8*)&Bs[ct * 16 + ln][lh * 8];
      acc[ct] = __builtin_amdgcn_mfma_f32_16x16x32_f16(a, bf, acc[ct], 0, 0, 0);
    }
  }

  #pragma unroll
  for (int ct = 0; ct < 4; ++ct) {
    const int n = nBase + ct * 16 + ln;
    #pragma unroll
    for (int j = 0; j < 4; ++j) {
      const int chL = wid * 16 + lh * 4 + j;
      const _Float16 v = (_Float16)acc[ct][j];
      if (chTile == 0)      Qh[((size_t)b * N_ + n) * CQ_ + chL] = v;
      else if (chTile == 1) Kh[((size_t)b * N_ + n) * CQ_ + chL] = v;
      else                  Vh[((size_t)b * C_ + (chTile - 2) * 64 + chL) * N_ + n] = v;
    }
  }
}

// ---------------------------------------------------------------------------
// Kernel 2: flash attention. Block = (b, 32 query rows). 8 waves, 512 threads.
// Wave w owns d range [w*64, w*64+64). M-step 128 keys. 2 barriers/iter.
// Es/Ps XOR-swizzled at 16B-chunk granularity: chunk ^= (row&7).
// ---------------------------------------------------------------------------
__global__ __launch_bounds__(512, 4) void flash_kernel(
    const float* __restrict__ x, const _Float16* __restrict__ Qh,
    const _Float16* __restrict__ Kh, const _Float16* __restrict__ Vh,
    const float* __restrict__ gamma, float* __restrict__ out)
{
  __shared__ float    Es[R_][128];   // 16 KB, swizzled
  __shared__ _Float16 Ps[R_][128];   // 8 KB,  swizzled
  __shared__ float m_s[R_], l_s[R_], sc_s[R_];

  const int tid = threadIdx.x;
  const int wid = tid >> 6, lane = tid & 63, ln = lane & 15, lh = lane >> 4;

  // bijective XCD swizzle: 512 blocks, 64 consecutive (same-b) blocks per XCD
  const int wg = (blockIdx.x & 7) * 64 + (blockIdx.x >> 3);
  const int b  = wg >> 7;            // 128 n-tiles per batch
  const int n0 = (wg & 127) * R_;
  const int d0w = wid * 64;

  if (tid < R_) { m_s[tid] = -3.0e38f; l_s[tid] = 0.0f; }

  // Q fragments (rows n0..n0+31), constant over the m loop
  half8 qf[2][2];
  #pragma unroll
  for (int rt = 0; rt < 2; ++rt)
    #pragma unroll
    for (int kk = 0; kk < 2; ++kk)
      qf[rt][kk] = *(const half8*)&Qh[((size_t)b * N_ + n0 + rt * 16 + ln) * CQ_ + kk * 32 + (lh << 3)];

  f32x4 acc[4][2] = {};

  const _Float16* vbase = Vh + ((size_t)b * C_ + d0w + ln) * (size_t)N_ + (lh << 3);
  const int cbase = (wid << 2) + (ln >> 2);   // phase1 Es chunk base (col = wid*16+ln)
  const int word  = ln & 3;

  __syncthreads();

  for (int m0 = 0; m0 < N_; m0 += M_) {
    // ---- Phase 1: E tile (32 x 128); wave w computes cols [w*16, w*16+16)
    {
      const _Float16* kp = Kh + ((size_t)b * N_ + m0 + (wid << 4) + ln) * CQ_ + (lh << 3);
      half8 kf0 = *(const half8*)kp;
      half8 kf1 = *(const half8*)(kp + 32);
      #pragma unroll
      for (int rt = 0; rt < 2; ++rt) {
        f32x4 e = {};
        e = __builtin_amdgcn_mfma_f32_16x16x32_f16(qf[rt][0], kf0, e, 0, 0, 0);
        e = __builtin_amdgcn_mfma_f32_16x16x32_f16(qf[rt][1], kf1, e, 0, 0, 0);
        #pragma unroll
        for (int j = 0; j < 4; ++j) {
          const int rlow = lh * 4 + j;           // row & 7 == rlow & 7
          Es[rt * 16 + rlow][((cbase ^ (rlow & 7)) << 2) + word] = e[j];
        }
      }
    }
    __syncthreads();

    // ---- Phase 2: online softmax. row r = tid>>4, slice s = tid&15 (8 cols each)
    {
      const int r = tid >> 4, s = tid & 15;
      const int sw = r & 7;
      const float* erow = &Es[r][0];
      const int c0 = (s ^ sw);
      f32x4 ev0 = *(const f32x4*)&erow[c0 << 2];          // cols s*4..s*4+3
      f32x4 ev1 = *(const f32x4*)&erow[(16 + c0) << 2];   // cols 64+s*4..+3
      float tmax = fmaxf(fmaxf(fmaxf(ev0[0], ev0[1]), fmaxf(ev0[2], ev0[3])),
                         fmaxf(fmaxf(ev1[0], ev1[1]), fmaxf(ev1[2], ev1[3])));
      tmax = fmaxf(tmax, __shfl_xor(tmax, 1));
      tmax = fmaxf(tmax, __shfl_xor(tmax, 2));
      tmax = fmaxf(tmax, __shfl_xor(tmax, 4));
      tmax = fmaxf(tmax, __shfl_xor(tmax, 8));
      const float mold = m_s[r];
      const float mnew = fmaxf(mold, tmax);
      const float scale = __expf(mold - mnew);
      half4 p0, p1;
      float psum = 0.f;
      #pragma unroll
      for (int u = 0; u < 4; ++u) {
        const float p = __expf(ev0[u] - mnew);
        p0[u] = (_Float16)p; psum += p;
      }
      #pragma unroll
      for (int u = 0; u < 4; ++u) {
        const float p = __expf(ev1[u] - mnew);
        p1[u] = (_Float16)p; psum += p;
      }
      psum += __shfl_xor(psum, 1);
      psum += __shfl_xor(psum, 2);
      psum += __shfl_xor(psum, 4);
      psum += __shfl_xor(psum, 8);
      _Float16* prow = &Ps[r][0];
      const int pc = ((s >> 1) ^ sw);
      *(half4*)&prow[(pc << 3) + ((s & 1) << 2)]       = p0;
      *(half4*)&prow[((8 + pc) << 3) + ((s & 1) << 2)] = p1;
      if (s == 0) { m_s[r] = mnew; l_s[r] = l_s[r] * scale + psum; sc_s[r] = scale; }
    }
    __syncthreads();

    // ---- Phase 3: rescale acc + PV MFMA.  (no trailing barrier needed:
    // next phase1 touches only Es; we read only Ps/sc_s here)
    {
      const float scl0 = sc_s[ln], scl1 = sc_s[16 + ln];
      const int swl = ln & 7;
      half8 pf[2][4];
      #pragma unroll
      for (int nt = 0; nt < 2; ++nt)
        #pragma unroll
        for (int kk = 0; kk < 4; ++kk)
          pf[nt][kk] = *(const half8*)&Ps[nt * 16 + ln][(((kk << 2) + lh) ^ swl) << 3];

      const _Float16* vp = vbase + m0;
      __builtin_amdgcn_s_setprio(1);
      #pragma unroll
      for (int dt = 0; dt < 4; ++dt) {
        half8 vf0 = *(const half8*)(vp);
        half8 vf1 = *(const half8*)(vp + 32);
        half8 vf2 = *(const half8*)(vp + 64);
        half8 vf3 = *(const half8*)(vp + 96);
        #pragma unroll
        for (int nt = 0; nt < 2; ++nt) {
          f32x4 a = acc[dt][nt];
          const float sc = nt ? scl1 : scl0;
          a[0] *= sc; a[1] *= sc; a[2] *= sc; a[3] *= sc;
          a = __builtin_amdgcn_mfma_f32_16x16x32_f16(vf0, pf[nt][0], a, 0, 0, 0);
          a = __builtin_amdgcn_mfma_f32_16x16x32_f16(vf1, pf[nt][1], a, 0, 0, 0);
          a = __builtin_amdgcn_mfma_f32_16x16x32_f16(vf2, pf[nt][2], a, 0, 0, 0);
          a = __builtin_amdgcn_mfma_f32_16x16x32_f16(vf3, pf[nt][3], a, 0, 0, 0);
          acc[dt][nt] = a;
        }
        vp += (size_t)16 * N_;
      }
      __builtin_amdgcn_s_setprio(0);
    }
  }

  // ---- Epilogue: normalize, gamma*out + x
  const float g = gamma[0];
  const float linv0 = 1.0f / l_s[ln];
  const float linv1 = 1.0f / l_s[16 + ln];
  #pragma unroll
  for (int dt = 0; dt < 4; ++dt) {
    #pragma unroll
    for (int j = 0; j < 4; ++j) {
      const size_t row = ((size_t)b * C_ + d0w + dt * 16 + lh * 4 + j) * N_ + n0;
      out[row + ln]      = g * acc[dt][0][j] * linv0 + x[row + ln];
      out[row + 16 + ln] = g * acc[dt][1][j] * linv1 + x[row + 16 + ln];
    }
  }
}

extern "C" void kernel_launch(void* const* d_in, const int* in_sizes, int n_in,
                              void* d_out, int out_size, void* d_ws, size_t ws_size,
                              hipStream_t stream) {
  const float* x     = (const float*)d_in[0];
  const float* Wq    = (const float*)d_in[1];
  const float* Wk    = (const float*)d_in[2];
  const float* Wv    = (const float*)d_in[3];
  const float* gamma = (const float*)d_in[4];
  float* out = (float*)d_out;

  _Float16* Qh = (_Float16*)d_ws;
  _Float16* Kh = Qh + (size_t)B_ * N_ * CQ_;
  _Float16* Vh = Kh + (size_t)B_ * N_ * CQ_;

  proj_kernel<<<dim3(64, 10, B_), 256, 0, stream>>>(x, Wq, Wk, Wv, Qh, Kh, Vh);
  flash_kernel<<<dim3(512), 512, 0, stream>>>(x, Qh, Kh, Vh, gamma, out);
}